// Round 1
// baseline (4511.709 us; speedup 1.0000x reference)
//
#include <hip/hip_runtime.h>
#include <cstddef>

// Problem constants
#define BATCH   8
#define SEQ     1024
#define DMODEL  1024
#define NHEAD   16
#define HDIM    64
#define D3      3072
#define NROWS   (BATCH * SEQ)   // 8192
#define LN_EPS  1e-5f

// ---------- bf16 <-> fp32 bit helpers (OCP bf16 == upper 16 bits of fp32) ----
__device__ __forceinline__ float b2f(unsigned short u) {
    union { unsigned int i; float f; } v; v.i = ((unsigned int)u) << 16; return v.f;
}
__device__ __forceinline__ float blo(unsigned int p) {
    union { unsigned int i; float f; } v; v.i = p << 16; return v.f;
}
__device__ __forceinline__ float bhi(unsigned int p) {
    union { unsigned int i; float f; } v; v.i = p & 0xffff0000u; return v.f;
}
__device__ __forceinline__ unsigned short f2bu(float f) {  // round-to-nearest-even
    union { float f; unsigned int i; } v; v.f = f;
    unsigned int r = v.i + 0x7fffu + ((v.i >> 16) & 1u);
    return (unsigned short)(r >> 16);
}

// =====================================================================
// K1: qkv = x @ in_proj_w^T + in_proj_b     (fp32 in, bf16 out)
// x: [8192,1024]  W: [3072,1024] (row-major, k contiguous)  C: [8192,3072]
// 128x128 tile, BK=16, 256 threads, 8x8 micro-tile
// =====================================================================
__global__ __launch_bounds__(256)
void qkv_gemm(const float* __restrict__ A, const float* __restrict__ Wt,
              const float* __restrict__ bias, unsigned short* __restrict__ C) {
    __shared__ float As[16][128];
    __shared__ float Bs[16][128];
    const int t  = threadIdx.x;
    const int tx = t & 15, ty = t >> 4;
    const int m0 = blockIdx.y * 128;
    const int n0 = blockIdx.x * 128;
    const int lr = t >> 2;          // 0..63
    const int lc = (t & 3) * 4;     // 0,4,8,12

    float acc[8][8];
#pragma unroll
    for (int i = 0; i < 8; ++i)
#pragma unroll
        for (int j = 0; j < 8; ++j) acc[i][j] = 0.f;

    for (int k0 = 0; k0 < DMODEL; k0 += 16) {
        float4 a0 = *(const float4*)(A  + (size_t)(m0 + lr)      * DMODEL + k0 + lc);
        float4 a1 = *(const float4*)(A  + (size_t)(m0 + lr + 64) * DMODEL + k0 + lc);
        float4 b0 = *(const float4*)(Wt + (size_t)(n0 + lr)      * DMODEL + k0 + lc);
        float4 b1 = *(const float4*)(Wt + (size_t)(n0 + lr + 64) * DMODEL + k0 + lc);
        __syncthreads();
        As[lc+0][lr] = a0.x; As[lc+1][lr] = a0.y; As[lc+2][lr] = a0.z; As[lc+3][lr] = a0.w;
        As[lc+0][lr+64] = a1.x; As[lc+1][lr+64] = a1.y; As[lc+2][lr+64] = a1.z; As[lc+3][lr+64] = a1.w;
        Bs[lc+0][lr] = b0.x; Bs[lc+1][lr] = b0.y; Bs[lc+2][lr] = b0.z; Bs[lc+3][lr] = b0.w;
        Bs[lc+0][lr+64] = b1.x; Bs[lc+1][lr+64] = b1.y; Bs[lc+2][lr+64] = b1.z; Bs[lc+3][lr+64] = b1.w;
        __syncthreads();
#pragma unroll
        for (int kk = 0; kk < 16; ++kk) {
            float av[8], bv[8];
            *(float4*)&av[0] = *(const float4*)&As[kk][ty * 8];
            *(float4*)&av[4] = *(const float4*)&As[kk][ty * 8 + 4];
            *(float4*)&bv[0] = *(const float4*)&Bs[kk][tx * 8];
            *(float4*)&bv[4] = *(const float4*)&Bs[kk][tx * 8 + 4];
#pragma unroll
            for (int i = 0; i < 8; ++i)
#pragma unroll
                for (int j = 0; j < 8; ++j) acc[i][j] += av[i] * bv[j];
        }
    }
    float bs[8];
#pragma unroll
    for (int j = 0; j < 8; ++j) bs[j] = bias[n0 + tx * 8 + j];
#pragma unroll
    for (int i = 0; i < 8; ++i) {
        const int m = m0 + ty * 8 + i;
        unsigned short us[8];
#pragma unroll
        for (int j = 0; j < 8; ++j) us[j] = f2bu(acc[i][j] + bs[j]);
        uint4 pv;
        pv.x = us[0] | ((unsigned int)us[1] << 16);
        pv.y = us[2] | ((unsigned int)us[3] << 16);
        pv.z = us[4] | ((unsigned int)us[5] << 16);
        pv.w = us[6] | ((unsigned int)us[7] << 16);
        *(uint4*)(C + (size_t)m * D3 + n0 + tx * 8) = pv;
    }
}

// =====================================================================
// K2: attention. One block per (b,q) row, 256 threads.
// qkv bf16 [8192,3072]; writes attn fp32 [8192,1024] and mean weights
// fp32 [8192,1024] (= [B,Sq,Sk]).
// =====================================================================
__global__ __launch_bounds__(256)
void attn_kernel(const unsigned short* __restrict__ qkv, const float* __restrict__ tdp,
                 float* __restrict__ attn, float* __restrict__ wout) {
    const int q = blockIdx.x, b = blockIdx.y, t = threadIdx.x;
    __shared__ float q_s[DMODEL];
    __shared__ float e_s[SEQ];
    __shared__ float wsum_s[SEQ];
    __shared__ float red_s[256];
    __shared__ float part_s[4][64];

    const float td = -fabsf(tdp[0]);
    const size_t rowq = (size_t)(b * SEQ + q) * D3;

    {   // q row -> fp32 LDS
        const unsigned int* qp = (const unsigned int*)(qkv + rowq);
        for (int i = t; i < DMODEL / 2; i += 256) {
            unsigned int p = qp[i];
            q_s[2 * i] = blo(p); q_s[2 * i + 1] = bhi(p);
        }
    }
    for (int i = t; i < SEQ; i += 256) wsum_s[i] = 0.f;
    __syncthreads();

    const float scale = 0.125f;  // 1/sqrt(64)
    for (int h = 0; h < NHEAD; ++h) {
        const float* qh = q_s + h * HDIM;
        // ---- pass 1: e_j = exp(score), partial row sum ----
        float lpart = 0.f;
#pragma unroll
        for (int i = 0; i < 4; ++i) {
            const int j = t + i * 256;
            const uint4* kp = (const uint4*)(qkv + (size_t)(b * SEQ + j) * D3 + DMODEL + h * HDIM);
            float s = 0.f;
#pragma unroll
            for (int u = 0; u < 8; ++u) {
                uint4 pk = kp[u];
                s += blo(pk.x) * qh[u*8+0] + bhi(pk.x) * qh[u*8+1]
                   + blo(pk.y) * qh[u*8+2] + bhi(pk.y) * qh[u*8+3]
                   + blo(pk.z) * qh[u*8+4] + bhi(pk.z) * qh[u*8+5]
                   + blo(pk.w) * qh[u*8+6] + bhi(pk.w) * qh[u*8+7];
            }
            s = s * scale + td * fabsf((float)(j - q));
            const float e = __expf(s);   // scores bounded ~|7|: no overflow; underflow->0 benign
            e_s[j] = e;
            lpart += e;
        }
        red_s[t] = lpart;
        __syncthreads();
        for (int off = 128; off > 0; off >>= 1) {
            if (t < off) red_s[t] += red_s[t + off];
            __syncthreads();
        }
        const float inv_l = 1.0f / red_s[0];
        // ---- pass 2a: normalize in place + head-mean accumulate ----
#pragma unroll
        for (int i = 0; i < 4; ++i) {
            const int j = t + i * 256;
            const float w = e_s[j] * inv_l;
            e_s[j] = w;
            wsum_s[j] += w * (1.0f / NHEAD);
        }
        __syncthreads();
        // ---- pass 2b: PV GEMV. thread -> (jgroup, dim) ----
        {
            const int d = t & 63, jg = t >> 6;
            const unsigned short* vp = qkv + (size_t)(b * SEQ + jg * 256) * D3 + 2 * DMODEL + h * HDIM + d;
            float acc = 0.f;
            for (int jj = 0; jj < 256; ++jj)
                acc += e_s[jg * 256 + jj] * b2f(vp[(size_t)jj * D3]);
            part_s[jg][d] = acc;
        }
        __syncthreads();
        if (t < 64) {
            const float sum = part_s[0][t] + part_s[1][t] + part_s[2][t] + part_s[3][t];
            attn[(size_t)(b * SEQ + q) * DMODEL + h * HDIM + t] = sum;
        }
        __syncthreads();
    }
    float* wrow = wout + (size_t)(b * SEQ + q) * SEQ;
    for (int i = t; i < SEQ; i += 256) wrow[i] = wsum_s[i];
}

// =====================================================================
// K3: y = attn @ out_proj_w^T + out_proj_b + x     (all fp32)
// attn: [8192,1024]  Wo: [1024,1024]  y: [8192,1024]
// =====================================================================
__global__ __launch_bounds__(256)
void outproj_gemm(const float* __restrict__ A, const float* __restrict__ Wt,
                  const float* __restrict__ bias, const float* __restrict__ X,
                  float* __restrict__ Y) {
    __shared__ float As[16][128];
    __shared__ float Bs[16][128];
    const int t  = threadIdx.x;
    const int tx = t & 15, ty = t >> 4;
    const int m0 = blockIdx.y * 128;
    const int n0 = blockIdx.x * 128;
    const int lr = t >> 2;
    const int lc = (t & 3) * 4;

    float acc[8][8];
#pragma unroll
    for (int i = 0; i < 8; ++i)
#pragma unroll
        for (int j = 0; j < 8; ++j) acc[i][j] = 0.f;

    for (int k0 = 0; k0 < DMODEL; k0 += 16) {
        float4 a0 = *(const float4*)(A  + (size_t)(m0 + lr)      * DMODEL + k0 + lc);
        float4 a1 = *(const float4*)(A  + (size_t)(m0 + lr + 64) * DMODEL + k0 + lc);
        float4 b0 = *(const float4*)(Wt + (size_t)(n0 + lr)      * DMODEL + k0 + lc);
        float4 b1 = *(const float4*)(Wt + (size_t)(n0 + lr + 64) * DMODEL + k0 + lc);
        __syncthreads();
        As[lc+0][lr] = a0.x; As[lc+1][lr] = a0.y; As[lc+2][lr] = a0.z; As[lc+3][lr] = a0.w;
        As[lc+0][lr+64] = a1.x; As[lc+1][lr+64] = a1.y; As[lc+2][lr+64] = a1.z; As[lc+3][lr+64] = a1.w;
        Bs[lc+0][lr] = b0.x; Bs[lc+1][lr] = b0.y; Bs[lc+2][lr] = b0.z; Bs[lc+3][lr] = b0.w;
        Bs[lc+0][lr+64] = b1.x; Bs[lc+1][lr+64] = b1.y; Bs[lc+2][lr+64] = b1.z; Bs[lc+3][lr+64] = b1.w;
        __syncthreads();
#pragma unroll
        for (int kk = 0; kk < 16; ++kk) {
            float av[8], bv[8];
            *(float4*)&av[0] = *(const float4*)&As[kk][ty * 8];
            *(float4*)&av[4] = *(const float4*)&As[kk][ty * 8 + 4];
            *(float4*)&bv[0] = *(const float4*)&Bs[kk][tx * 8];
            *(float4*)&bv[4] = *(const float4*)&Bs[kk][tx * 8 + 4];
#pragma unroll
            for (int i = 0; i < 8; ++i)
#pragma unroll
                for (int j = 0; j < 8; ++j) acc[i][j] += av[i] * bv[j];
        }
    }
    float bs[8];
#pragma unroll
    for (int j = 0; j < 8; ++j) bs[j] = bias[n0 + tx * 8 + j];
#pragma unroll
    for (int i = 0; i < 8; ++i) {
        const int m = m0 + ty * 8 + i;
        const float* xr = X + (size_t)m * DMODEL + n0 + tx * 8;
        float4 x0 = *(const float4*)(xr);
        float4 x1 = *(const float4*)(xr + 4);
        float4 o0, o1;
        o0.x = acc[i][0] + bs[0] + x0.x;  o0.y = acc[i][1] + bs[1] + x0.y;
        o0.z = acc[i][2] + bs[2] + x0.z;  o0.w = acc[i][3] + bs[3] + x0.w;
        o1.x = acc[i][4] + bs[4] + x1.x;  o1.y = acc[i][5] + bs[5] + x1.y;
        o1.z = acc[i][6] + bs[6] + x1.z;  o1.w = acc[i][7] + bs[7] + x1.w;
        float* yr = Y + (size_t)m * DMODEL + n0 + tx * 8;
        *(float4*)(yr)     = o0;
        *(float4*)(yr + 4) = o1;
    }
}

// =====================================================================
// K4: LayerNorm per row -> final out
// =====================================================================
__global__ __launch_bounds__(256)
void ln_kernel(const float* __restrict__ Y, const float* __restrict__ lnw,
               const float* __restrict__ lnb, float* __restrict__ out) {
    const int row = blockIdx.x, t = threadIdx.x;
    __shared__ float rs[256], rq[256];
    const float4 v = ((const float4*)(Y + (size_t)row * DMODEL))[t];
    rs[t] = v.x + v.y + v.z + v.w;
    rq[t] = v.x * v.x + v.y * v.y + v.z * v.z + v.w * v.w;
    __syncthreads();
    for (int off = 128; off > 0; off >>= 1) {
        if (t < off) { rs[t] += rs[t + off]; rq[t] += rq[t + off]; }
        __syncthreads();
    }
    const float mu   = rs[0] * (1.0f / DMODEL);
    const float var  = rq[0] * (1.0f / DMODEL) - mu * mu;
    const float rstd = rsqrtf(var + LN_EPS);
    const float4 w  = ((const float4*)lnw)[t];
    const float4 bb = ((const float4*)lnb)[t];
    float4 o;
    o.x = (v.x - mu) * rstd * w.x + bb.x;
    o.y = (v.y - mu) * rstd * w.y + bb.y;
    o.z = (v.z - mu) * rstd * w.z + bb.z;
    o.w = (v.w - mu) * rstd * w.w + bb.w;
    ((float4*)(out + (size_t)row * DMODEL))[t] = o;
}

// =====================================================================
extern "C" void kernel_launch(void* const* d_in, const int* in_sizes, int n_in,
                              void* d_out, int out_size, void* d_ws, size_t ws_size,
                              hipStream_t stream) {
    (void)in_sizes; (void)n_in; (void)out_size; (void)ws_size;
    const float* x    = (const float*)d_in[0];
    const float* td   = (const float*)d_in[1];
    const float* wqkv = (const float*)d_in[2];
    const float* bqkv = (const float*)d_in[3];
    const float* wo   = (const float*)d_in[4];
    const float* bo   = (const float*)d_in[5];
    const float* lnw  = (const float*)d_in[6];
    const float* lnb  = (const float*)d_in[7];

    float* out_ln = (float*)d_out;                         // [8192,1024] final out
    float* out_w  = (float*)d_out + (size_t)NROWS * SEQ;   // [8,1024,1024] mean weights

    // ws layout: qkv bf16 [8192,3072] at 0 (50.3 MB); y fp32 [8192,1024]
    // reuses offset 0 after qkv is dead (stream-ordered).
    unsigned short* qkv = (unsigned short*)d_ws;
    float*          y   = (float*)d_ws;

    // attn (fp32) temporarily lives in d_out first half; overwritten by LN.
    float* attn = out_ln;

    qkv_gemm    <<<dim3(D3 / 128, NROWS / 128), 256, 0, stream>>>(x, wqkv, bqkv, qkv);
    attn_kernel <<<dim3(SEQ, BATCH),            256, 0, stream>>>(qkv, td, attn, out_w);
    outproj_gemm<<<dim3(DMODEL / 128, NROWS / 128), 256, 0, stream>>>(attn, wo, bo, x, y);
    ln_kernel   <<<NROWS,                       256, 0, stream>>>(y, lnw, lnb, out_ln);
}

// Round 2
// 1261.451 us; speedup vs baseline: 3.5766x; 3.5766x over previous
//
#include <hip/hip_runtime.h>
#include <cstddef>

// Problem constants
#define BATCH   8
#define SEQ     1024
#define DMODEL  1024
#define NHEAD   16
#define HDIM    64
#define D3      3072
#define NROWS   (BATCH * SEQ)   // 8192
#define LN_EPS  1e-5f

typedef __attribute__((ext_vector_type(4))) float f32x4;
typedef __attribute__((ext_vector_type(8))) short bf16x8;

// ---------- bf16 <-> fp32 bit helpers ----------
__device__ __forceinline__ float b2f(unsigned short u) {
    union { unsigned int i; float f; } v; v.i = ((unsigned int)u) << 16; return v.f;
}
__device__ __forceinline__ unsigned short f2bu(float f) {  // round-to-nearest-even
    union { float f; unsigned int i; } v; v.f = f;
    unsigned int r = v.i + 0x7fffu + ((v.i >> 16) & 1u);
    return (unsigned short)(r >> 16);
}

// =====================================================================
// K1: qkv = x @ in_proj_w^T + in_proj_b   (fp32 in, bf16 out)
// Q,K -> qk [8192, 2048] row-major (Q cols 0..1023, K cols 1024..2047)
// V   -> vt [8*16, 64, 1024] = [b,h][d][key]  (transposed for PV B-frags)
// 128x128 tile, BK=16, 256 threads, 8x8 micro-tile
// =====================================================================
__global__ __launch_bounds__(256)
void qkv_gemm(const float* __restrict__ A, const float* __restrict__ Wt,
              const float* __restrict__ bias,
              unsigned short* __restrict__ qk, unsigned short* __restrict__ vt) {
    __shared__ float As[16][128];
    __shared__ float Bs[16][128];
    const int t  = threadIdx.x;
    const int tx = t & 15, ty = t >> 4;
    const int m0 = blockIdx.y * 128;
    const int n0 = blockIdx.x * 128;
    const int lr = t >> 2;          // 0..63
    const int lc = (t & 3) * 4;     // 0,4,8,12

    float acc[8][8];
#pragma unroll
    for (int i = 0; i < 8; ++i)
#pragma unroll
        for (int j = 0; j < 8; ++j) acc[i][j] = 0.f;

    for (int k0 = 0; k0 < DMODEL; k0 += 16) {
        float4 a0 = *(const float4*)(A  + (size_t)(m0 + lr)      * DMODEL + k0 + lc);
        float4 a1 = *(const float4*)(A  + (size_t)(m0 + lr + 64) * DMODEL + k0 + lc);
        float4 b0 = *(const float4*)(Wt + (size_t)(n0 + lr)      * DMODEL + k0 + lc);
        float4 b1 = *(const float4*)(Wt + (size_t)(n0 + lr + 64) * DMODEL + k0 + lc);
        __syncthreads();
        As[lc+0][lr] = a0.x; As[lc+1][lr] = a0.y; As[lc+2][lr] = a0.z; As[lc+3][lr] = a0.w;
        As[lc+0][lr+64] = a1.x; As[lc+1][lr+64] = a1.y; As[lc+2][lr+64] = a1.z; As[lc+3][lr+64] = a1.w;
        Bs[lc+0][lr] = b0.x; Bs[lc+1][lr] = b0.y; Bs[lc+2][lr] = b0.z; Bs[lc+3][lr] = b0.w;
        Bs[lc+0][lr+64] = b1.x; Bs[lc+1][lr+64] = b1.y; Bs[lc+2][lr+64] = b1.z; Bs[lc+3][lr+64] = b1.w;
        __syncthreads();
#pragma unroll
        for (int kk = 0; kk < 16; ++kk) {
            float av[8], bv[8];
            *(float4*)&av[0] = *(const float4*)&As[kk][ty * 8];
            *(float4*)&av[4] = *(const float4*)&As[kk][ty * 8 + 4];
            *(float4*)&bv[0] = *(const float4*)&Bs[kk][tx * 8];
            *(float4*)&bv[4] = *(const float4*)&Bs[kk][tx * 8 + 4];
#pragma unroll
            for (int i = 0; i < 8; ++i)
#pragma unroll
                for (int j = 0; j < 8; ++j) acc[i][j] += av[i] * bv[j];
        }
    }
    float bs[8];
#pragma unroll
    for (int j = 0; j < 8; ++j) bs[j] = bias[n0 + tx * 8 + j];

    if (n0 < 2048) {
        // Q or K: row-major into qk [8192, 2048]
#pragma unroll
        for (int i = 0; i < 8; ++i) {
            const int m = m0 + ty * 8 + i;
            unsigned short us[8];
#pragma unroll
            for (int j = 0; j < 8; ++j) us[j] = f2bu(acc[i][j] + bs[j]);
            uint4 pv;
            pv.x = us[0] | ((unsigned int)us[1] << 16);
            pv.y = us[2] | ((unsigned int)us[3] << 16);
            pv.z = us[4] | ((unsigned int)us[5] << 16);
            pv.w = us[6] | ((unsigned int)us[7] << 16);
            *(uint4*)(qk + (size_t)m * 2048 + n0 + tx * 8) = pv;
        }
    } else {
        // V: transposed into vt[(b*16+h)*64 + d][key]
        const int b_   = m0 >> 10;
        const int key0 = (m0 & 1023) + ty * 8;
#pragma unroll
        for (int j = 0; j < 8; ++j) {
            const int n = n0 + tx * 8 + j - 2048;   // 0..1023
            const int h = n >> 6, d = n & 63;
            unsigned short us[8];
#pragma unroll
            for (int i = 0; i < 8; ++i) us[i] = f2bu(acc[i][j] + bs[j]);
            uint4 pv;
            pv.x = us[0] | ((unsigned int)us[1] << 16);
            pv.y = us[2] | ((unsigned int)us[3] << 16);
            pv.z = us[4] | ((unsigned int)us[5] << 16);
            pv.w = us[6] | ((unsigned int)us[7] << 16);
            *(uint4*)(vt + ((size_t)((b_ * 16 + h) * 64 + d)) * 1024 + key0) = pv;
        }
    }
}

// =====================================================================
// K2: MFMA attention. Block = (qtile of 16 rows, batch). 256 threads.
// Writes attn fp32 [8192,1024] and head-mean weights fp32 [8192,1024].
// =====================================================================
__global__ __launch_bounds__(256, 2)
void attn_mfma(const unsigned short* __restrict__ qk,   // [8192][2048]
               const unsigned short* __restrict__ vt,   // [128][64][1024]
               const float* __restrict__ tdp,
               float* __restrict__ attn,                 // [8192][1024]
               float* __restrict__ wout) {               // [8192][1024]
    const int qt = blockIdx.x;      // 0..63
    const int b  = blockIdx.y;      // 0..7
    const int t  = threadIdx.x;
    const int w  = t >> 6;          // wave 0..3
    const int lane = t & 63;
    const int g  = lane >> 4;       // quad group 0..3
    const int c  = lane & 15;

    const int q0 = qt * 16;
    const float td = -fabsf(tdp[0]);

    __shared__ unsigned short P_s[16][1032];   // normalized weights, bf16
    __shared__ float rs_s[4][16];              // per-wave row sums

    float wsum[16][4];                          // head-mean accumulator (C layout)
#pragma unroll
    for (int tt = 0; tt < 16; ++tt)
#pragma unroll
        for (int r = 0; r < 4; ++r) wsum[tt][r] = 0.f;

    const int key_base = w * 256;               // wave's key range in QK^T
    const size_t qrow = (size_t)(b * 1024 + q0 + c) * 2048;  // A-frag row (m=c)

    for (int h = 0; h < NHEAD; ++h) {
        // ---- A-frags for QK^T (Q rows, 2 k-steps over HDIM=64) ----
        bf16x8 qa0 = *(const bf16x8*)(qk + qrow + h * 64 + 0  + g * 8);
        bf16x8 qa1 = *(const bf16x8*)(qk + qrow + h * 64 + 32 + g * 8);

        // ---- QK^T: 16 output tiles per wave, 2 MFMA each ----
        f32x4 acc[16];
#pragma unroll
        for (int tt = 0; tt < 16; ++tt) {
            const int key = key_base + tt * 16 + c;      // B-frag n = c
            const unsigned short* kp = qk + (size_t)(b * 1024 + key) * 2048
                                          + 1024 + h * 64 + g * 8;
            bf16x8 kb0 = *(const bf16x8*)(kp);
            bf16x8 kb1 = *(const bf16x8*)(kp + 32);
            f32x4 z = {0.f, 0.f, 0.f, 0.f};
            z = __builtin_amdgcn_mfma_f32_16x16x32_bf16(qa0, kb0, z, 0, 0, 0);
            z = __builtin_amdgcn_mfma_f32_16x16x32_bf16(qa1, kb1, z, 0, 0, 0);
            acc[tt] = z;
        }

        // ---- scale + time-decay bias + exp + partial row sums ----
        float rsum[4] = {0.f, 0.f, 0.f, 0.f};
#pragma unroll
        for (int tt = 0; tt < 16; ++tt) {
            const float kf = (float)(key_base + tt * 16 + c);
#pragma unroll
            for (int r = 0; r < 4; ++r) {
                const float qf = (float)(q0 + g * 4 + r);
                const float s = acc[tt][r] * 0.125f + td * fabsf(kf - qf);
                const float e = __expf(s);   // bounded scores: no overflow
                acc[tt][r] = e;
                rsum[r] += e;
            }
        }
        // reduce over the 16 column-lanes of each quad-group
#pragma unroll
        for (int r = 0; r < 4; ++r) {
            rsum[r] += __shfl_xor(rsum[r], 1, 64);
            rsum[r] += __shfl_xor(rsum[r], 2, 64);
            rsum[r] += __shfl_xor(rsum[r], 4, 64);
            rsum[r] += __shfl_xor(rsum[r], 8, 64);
        }
        if (c == 0) {
#pragma unroll
            for (int r = 0; r < 4; ++r) rs_s[w][g * 4 + r] = rsum[r];
        }
        __syncthreads();
        float invl[4];
#pragma unroll
        for (int r = 0; r < 4; ++r) {
            const int row = g * 4 + r;
            invl[r] = 1.0f / (rs_s[0][row] + rs_s[1][row] + rs_s[2][row] + rs_s[3][row]);
        }

        // ---- normalize, accumulate head-mean, stash P (bf16) in LDS ----
#pragma unroll
        for (int tt = 0; tt < 16; ++tt) {
#pragma unroll
            for (int r = 0; r < 4; ++r) {
                const float wv = acc[tt][r] * invl[r];
                wsum[tt][r] += wv;
                P_s[g * 4 + r][key_base + tt * 16 + c] = f2bu(wv);
            }
        }
        __syncthreads();

        // ---- PV: each wave computes 16 q-rows x 16 d-cols ----
        f32x4 accO = {0.f, 0.f, 0.f, 0.f};
        const unsigned short* vhp = vt + (size_t)((b * 16 + h) * 64 + w * 16 + c) * 1024;
#pragma unroll 8
        for (int ks = 0; ks < 32; ++ks) {
            bf16x8 pa = *(const bf16x8*)(&P_s[c][ks * 32 + g * 8]);       // A: P[m=c][k]
            bf16x8 vb = *(const bf16x8*)(vhp + ks * 32 + g * 8);          // B: V^T[n][k]
            accO = __builtin_amdgcn_mfma_f32_16x16x32_bf16(pa, vb, accO, 0, 0, 0);
        }
        float* op = attn + (size_t)(b * 1024 + q0) * 1024 + h * 64 + w * 16 + c;
#pragma unroll
        for (int r = 0; r < 4; ++r)
            op[(size_t)(g * 4 + r) * 1024] = accO[r];
        __syncthreads();   // guard P_s before next head overwrites
    }

    // ---- head-mean attention weights out ----
#pragma unroll
    for (int tt = 0; tt < 16; ++tt) {
#pragma unroll
        for (int r = 0; r < 4; ++r) {
            wout[(size_t)(b * 1024 + q0 + g * 4 + r) * 1024 + key_base + tt * 16 + c]
                = wsum[tt][r] * (1.0f / NHEAD);
        }
    }
}

// =====================================================================
// K3: y = attn @ out_proj_w^T + out_proj_b + x     (all fp32)
// =====================================================================
__global__ __launch_bounds__(256)
void outproj_gemm(const float* __restrict__ A, const float* __restrict__ Wt,
                  const float* __restrict__ bias, const float* __restrict__ X,
                  float* __restrict__ Y) {
    __shared__ float As[16][128];
    __shared__ float Bs[16][128];
    const int t  = threadIdx.x;
    const int tx = t & 15, ty = t >> 4;
    const int m0 = blockIdx.y * 128;
    const int n0 = blockIdx.x * 128;
    const int lr = t >> 2;
    const int lc = (t & 3) * 4;

    float acc[8][8];
#pragma unroll
    for (int i = 0; i < 8; ++i)
#pragma unroll
        for (int j = 0; j < 8; ++j) acc[i][j] = 0.f;

    for (int k0 = 0; k0 < DMODEL; k0 += 16) {
        float4 a0 = *(const float4*)(A  + (size_t)(m0 + lr)      * DMODEL + k0 + lc);
        float4 a1 = *(const float4*)(A  + (size_t)(m0 + lr + 64) * DMODEL + k0 + lc);
        float4 b0 = *(const float4*)(Wt + (size_t)(n0 + lr)      * DMODEL + k0 + lc);
        float4 b1 = *(const float4*)(Wt + (size_t)(n0 + lr + 64) * DMODEL + k0 + lc);
        __syncthreads();
        As[lc+0][lr] = a0.x; As[lc+1][lr] = a0.y; As[lc+2][lr] = a0.z; As[lc+3][lr] = a0.w;
        As[lc+0][lr+64] = a1.x; As[lc+1][lr+64] = a1.y; As[lc+2][lr+64] = a1.z; As[lc+3][lr+64] = a1.w;
        Bs[lc+0][lr] = b0.x; Bs[lc+1][lr] = b0.y; Bs[lc+2][lr] = b0.z; Bs[lc+3][lr] = b0.w;
        Bs[lc+0][lr+64] = b1.x; Bs[lc+1][lr+64] = b1.y; Bs[lc+2][lr+64] = b1.z; Bs[lc+3][lr+64] = b1.w;
        __syncthreads();
#pragma unroll
        for (int kk = 0; kk < 16; ++kk) {
            float av[8], bv[8];
            *(float4*)&av[0] = *(const float4*)&As[kk][ty * 8];
            *(float4*)&av[4] = *(const float4*)&As[kk][ty * 8 + 4];
            *(float4*)&bv[0] = *(const float4*)&Bs[kk][tx * 8];
            *(float4*)&bv[4] = *(const float4*)&Bs[kk][tx * 8 + 4];
#pragma unroll
            for (int i = 0; i < 8; ++i)
#pragma unroll
                for (int j = 0; j < 8; ++j) acc[i][j] += av[i] * bv[j];
        }
    }
    float bs[8];
#pragma unroll
    for (int j = 0; j < 8; ++j) bs[j] = bias[n0 + tx * 8 + j];
#pragma unroll
    for (int i = 0; i < 8; ++i) {
        const int m = m0 + ty * 8 + i;
        const float* xr = X + (size_t)m * DMODEL + n0 + tx * 8;
        float4 x0 = *(const float4*)(xr);
        float4 x1 = *(const float4*)(xr + 4);
        float4 o0, o1;
        o0.x = acc[i][0] + bs[0] + x0.x;  o0.y = acc[i][1] + bs[1] + x0.y;
        o0.z = acc[i][2] + bs[2] + x0.z;  o0.w = acc[i][3] + bs[3] + x0.w;
        o1.x = acc[i][4] + bs[4] + x1.x;  o1.y = acc[i][5] + bs[5] + x1.y;
        o1.z = acc[i][6] + bs[6] + x1.z;  o1.w = acc[i][7] + bs[7] + x1.w;
        float* yr = Y + (size_t)m * DMODEL + n0 + tx * 8;
        *(float4*)(yr)     = o0;
        *(float4*)(yr + 4) = o1;
    }
}

// =====================================================================
// K4: LayerNorm per row -> final out
// =====================================================================
__global__ __launch_bounds__(256)
void ln_kernel(const float* __restrict__ Y, const float* __restrict__ lnw,
               const float* __restrict__ lnb, float* __restrict__ out) {
    const int row = blockIdx.x, t = threadIdx.x;
    __shared__ float rs[256], rq[256];
    const float4 v = ((const float4*)(Y + (size_t)row * DMODEL))[t];
    rs[t] = v.x + v.y + v.z + v.w;
    rq[t] = v.x * v.x + v.y * v.y + v.z * v.z + v.w * v.w;
    __syncthreads();
    for (int off = 128; off > 0; off >>= 1) {
        if (t < off) { rs[t] += rs[t + off]; rq[t] += rq[t + off]; }
        __syncthreads();
    }
    const float mu   = rs[0] * (1.0f / DMODEL);
    const float var  = rq[0] * (1.0f / DMODEL) - mu * mu;
    const float rstd = rsqrtf(var + LN_EPS);
    const float4 w  = ((const float4*)lnw)[t];
    const float4 bb = ((const float4*)lnb)[t];
    float4 o;
    o.x = (v.x - mu) * rstd * w.x + bb.x;
    o.y = (v.y - mu) * rstd * w.y + bb.y;
    o.z = (v.z - mu) * rstd * w.z + bb.z;
    o.w = (v.w - mu) * rstd * w.w + bb.w;
    ((float4*)(out + (size_t)row * DMODEL))[t] = o;
}

// =====================================================================
extern "C" void kernel_launch(void* const* d_in, const int* in_sizes, int n_in,
                              void* d_out, int out_size, void* d_ws, size_t ws_size,
                              hipStream_t stream) {
    (void)in_sizes; (void)n_in; (void)out_size; (void)ws_size;
    const float* x    = (const float*)d_in[0];
    const float* td   = (const float*)d_in[1];
    const float* wqkv = (const float*)d_in[2];
    const float* bqkv = (const float*)d_in[3];
    const float* wo   = (const float*)d_in[4];
    const float* bo   = (const float*)d_in[5];
    const float* lnw  = (const float*)d_in[6];
    const float* lnb  = (const float*)d_in[7];

    float* out_ln = (float*)d_out;                         // [8192,1024] final out
    float* out_w  = (float*)d_out + (size_t)NROWS * SEQ;   // [8,1024,1024] mean weights

    // ws layout: qk bf16 [8192,2048] at 0 (33.55 MB); vt bf16 [128,64,1024]
    // at +33.55 MB (16.78 MB). y fp32 [8192,1024] reuses offset 0 after attn.
    unsigned short* qk = (unsigned short*)d_ws;
    unsigned short* vt = (unsigned short*)d_ws + (size_t)NROWS * 2048;
    float*          y  = (float*)d_ws;

    // attn (fp32) temporarily lives in d_out first half; overwritten by LN.
    float* attn = out_ln;

    qkv_gemm    <<<dim3(D3 / 128, NROWS / 128), 256, 0, stream>>>(x, wqkv, bqkv, qk, vt);
    attn_mfma   <<<dim3(SEQ / 16, BATCH),       256, 0, stream>>>(qk, vt, td, attn, out_w);
    outproj_gemm<<<dim3(DMODEL / 128, NROWS / 128), 256, 0, stream>>>(attn, wo, bo, x, y);
    ln_kernel   <<<NROWS,                       256, 0, stream>>>(y, lnw, lnb, out_ln);
}

// Round 3
// 571.788 us; speedup vs baseline: 7.8905x; 2.2062x over previous
//
#include <hip/hip_runtime.h>
#include <cstddef>

// Problem constants
#define BATCH   8
#define SEQ     1024
#define DMODEL  1024
#define NHEAD   16
#define HDIM    64
#define D3      3072
#define NROWS   (BATCH * SEQ)   // 8192
#define LN_EPS  1e-5f

typedef __attribute__((ext_vector_type(4))) float f32x4;
typedef __attribute__((ext_vector_type(8))) short bf16x8;

// ---------- bf16 helpers ----------
__device__ __forceinline__ float b2f(unsigned short u) {
    union { unsigned int i; float f; } v; v.i = ((unsigned int)u) << 16; return v.f;
}
__device__ __forceinline__ unsigned short f2bu(float f) {  // round-to-nearest-even
    union { float f; unsigned int i; } v; v.f = f;
    unsigned int r = v.i + 0x7fffu + ((v.i >> 16) & 1u);
    return (unsigned short)(r >> 16);
}
// async global->LDS, 16B per lane (wave-uniform base + lane*16)
__device__ __forceinline__ void gl16(const void* g, void* l) {
    __builtin_amdgcn_global_load_lds(
        (const __attribute__((address_space(1))) unsigned int*)g,
        (__attribute__((address_space(3))) unsigned int*)l, 16, 0, 0);
}

// =====================================================================
// K0: fp32 -> bf16 conversion of x, in_proj_w, out_proj_w
// =====================================================================
#define NG_X  1048576   // 8192*1024/8
#define NG_WQ 393216    // 3072*1024/8
#define NG_WO 131072    // 1024*1024/8
__global__ __launch_bounds__(256)
void cvt_bf16(const float* __restrict__ x, const float* __restrict__ wq,
              const float* __restrict__ wo,
              unsigned short* __restrict__ xb, unsigned short* __restrict__ wqb,
              unsigned short* __restrict__ wob) {
    const int gidx = blockIdx.x * 256 + threadIdx.x;
    const float* src; unsigned short* dst; size_t off;
    if (gidx < NG_X)              { src = x;  dst = xb;  off = (size_t)gidx * 8; }
    else if (gidx < NG_X + NG_WQ) { src = wq; dst = wqb; off = (size_t)(gidx - NG_X) * 8; }
    else                          { src = wo; dst = wob; off = (size_t)(gidx - NG_X - NG_WQ) * 8; }
    float4 v0 = *(const float4*)(src + off);
    float4 v1 = *(const float4*)(src + off + 4);
    uint4 pv;
    pv.x = f2bu(v0.x) | ((unsigned int)f2bu(v0.y) << 16);
    pv.y = f2bu(v0.z) | ((unsigned int)f2bu(v0.w) << 16);
    pv.z = f2bu(v1.x) | ((unsigned int)f2bu(v1.y) << 16);
    pv.w = f2bu(v1.z) | ((unsigned int)f2bu(v1.w) << 16);
    *(uint4*)(dst + off) = pv;
}

// =====================================================================
// K1: qkv MFMA GEMM. C[8192,3072] = xb @ wb^T + bias  (bf16 in, bf16 out)
// Q,K -> qk [8192,2048] row-major; V -> vt [(b*16+h)*64+d][key] transposed.
// 128x128 tile, BK=32, 4 waves (2x2), 16x16x32 MFMA, global_load_lds x16B.
// =====================================================================
__global__ __launch_bounds__(256)
void qkv_mfma(const unsigned short* __restrict__ xb,    // [8192][1024]
              const unsigned short* __restrict__ wb,    // [3072][1024]
              const float* __restrict__ bias,           // [3072]
              unsigned short* __restrict__ qk,          // [8192][2048]
              unsigned short* __restrict__ vt) {        // [128*64][1024]
    __shared__ unsigned short smem[8192];               // As 4096 | Bs 4096 (16 KB)
    unsigned short* As = smem;
    unsigned short* Bs = smem + 4096;

    const int t = threadIdx.x;
    const int w = t >> 6, lane = t & 63;
    const int wm = w >> 1, wn = w & 1;
    const int g = lane >> 4, c = lane & 15;
    const int m0 = blockIdx.y * 128, n0 = blockIdx.x * 128;

    const int srow = t >> 2;            // 0..63
    const int scol = (t & 3) * 8;       // 0,8,16,24
    const unsigned short* ga = xb + (size_t)(m0 + srow) * 1024 + scol;
    const unsigned short* gb = wb + (size_t)(n0 + srow) * 1024 + scol;

    f32x4 acc[4][4];
#pragma unroll
    for (int i = 0; i < 4; ++i)
#pragma unroll
        for (int j = 0; j < 4; ++j) acc[i][j] = (f32x4){0.f, 0.f, 0.f, 0.f};

    for (int k0 = 0; k0 < 1024; k0 += 32) {
        gl16(ga + k0,             As + t * 8);
        gl16(ga + 64 * 1024 + k0, As + 2048 + t * 8);
        gl16(gb + k0,             Bs + t * 8);
        gl16(gb + 64 * 1024 + k0, Bs + 2048 + t * 8);
        __syncthreads();                         // drains vmcnt -> tile visible
        bf16x8 af[4], bf[4];
#pragma unroll
        for (int i = 0; i < 4; ++i)
            af[i] = *(const bf16x8*)(As + (wm * 64 + i * 16 + c) * 32 + g * 8);
#pragma unroll
        for (int j = 0; j < 4; ++j)
            bf[j] = *(const bf16x8*)(Bs + (wn * 64 + j * 16 + c) * 32 + g * 8);
#pragma unroll
        for (int i = 0; i < 4; ++i)
#pragma unroll
            for (int j = 0; j < 4; ++j)
                acc[i][j] = __builtin_amdgcn_mfma_f32_16x16x32_bf16(af[i], bf[j], acc[i][j], 0, 0, 0);
        __syncthreads();                         // protect tile before next overwrite
    }

    float bsv[4];
#pragma unroll
    for (int j = 0; j < 4; ++j) bsv[j] = bias[n0 + wn * 64 + j * 16 + c];

    unsigned short* eslice = smem + w * 2048;    // 4 KB per-wave epilogue slice

    if (n0 < 2048) {
        // ---- Q/K: row-major bf16 into qk ----
#pragma unroll
        for (int half = 0; half < 2; ++half) {
#pragma unroll
            for (int ii = 0; ii < 2; ++ii) {
                const int i = half * 2 + ii;
#pragma unroll
                for (int j = 0; j < 4; ++j)
#pragma unroll
                    for (int r = 0; r < 4; ++r)
                        eslice[(ii * 16 + g * 4 + r) * 64 + j * 16 + c] = f2bu(acc[i][j][r] + bsv[j]);
            }
#pragma unroll
            for (int u = 0; u < 4; ++u) {
                const int mloc = u * 8 + (lane >> 3);       // 0..31
                const int ncol = (lane & 7) * 8;
                bf16x8 row = *(const bf16x8*)(eslice + mloc * 64 + ncol);
                const int m = m0 + wm * 64 + half * 32 + mloc;
                *(bf16x8*)(qk + (size_t)m * 2048 + n0 + wn * 64 + ncol) = row;
            }
        }
    } else {
        // ---- V: transposed into vt[(b*16+h)*64+d][key], XOR-swizzled LDS ----
        const int b_    = m0 >> 10;
        const int key0  = (m0 & 1023) + wm * 64;
        const int hbase = (n0 + wn * 64 - 2048) >> 6;
#pragma unroll
        for (int half = 0; half < 2; ++half) {
#pragma unroll
            for (int jj = 0; jj < 2; ++jj) {
                const int j = half * 2 + jj;
                const int nloc = jj * 16 + c;               // 0..31
#pragma unroll
                for (int i = 0; i < 4; ++i)
#pragma unroll
                    for (int r = 0; r < 4; ++r) {
                        const int mloc  = i * 16 + g * 4 + r;
                        const int mphys = mloc ^ ((nloc & 7) << 3);
                        eslice[nloc * 64 + mphys] = f2bu(acc[i][j][r] + bsv[j]);
                    }
            }
#pragma unroll
            for (int u = 0; u < 4; ++u) {
                const int nloc  = u * 8 + (lane >> 3);      // 0..31
                const int mb    = lane & 7;
                const int mphys = (mb ^ (nloc & 7)) * 8;
                bf16x8 row = *(const bf16x8*)(eslice + nloc * 64 + mphys);
                const int d = half * 32 + nloc;
                *(bf16x8*)(vt + ((size_t)((b_ * 16 + hbase) * 64 + d)) * 1024 + key0 + mb * 8) = row;
            }
        }
    }
}

// =====================================================================
// K2: MFMA attention. Block = (qtile of 16 rows, batch). 256 threads.
// Writes attn bf16 [8192,1024] and head-mean weights fp32 [8192,1024].
// =====================================================================
__global__ __launch_bounds__(256, 2)
void attn_mfma(const unsigned short* __restrict__ qk,   // [8192][2048]
               const unsigned short* __restrict__ vt,   // [128][64][1024]
               const float* __restrict__ tdp,
               unsigned short* __restrict__ attnb,       // [8192][1024] bf16
               float* __restrict__ wout) {               // [8192][1024]
    const int qt = blockIdx.x;      // 0..63
    const int b  = blockIdx.y;      // 0..7
    const int t  = threadIdx.x;
    const int w  = t >> 6;          // wave 0..3
    const int lane = t & 63;
    const int g  = lane >> 4;       // quad group 0..3
    const int c  = lane & 15;

    const int q0 = qt * 16;
    const float td = -fabsf(tdp[0]);

    __shared__ unsigned short P_s[16][1032];   // normalized weights, bf16
    __shared__ float rs_s[4][16];              // per-wave row sums

    float wsum[16][4];                          // head-mean accumulator (C layout)
#pragma unroll
    for (int tt = 0; tt < 16; ++tt)
#pragma unroll
        for (int r = 0; r < 4; ++r) wsum[tt][r] = 0.f;

    const int key_base = w * 256;               // wave's key range in QK^T
    const size_t qrow = (size_t)(b * 1024 + q0 + c) * 2048;  // A-frag row (m=c)

    for (int h = 0; h < NHEAD; ++h) {
        bf16x8 qa0 = *(const bf16x8*)(qk + qrow + h * 64 + 0  + g * 8);
        bf16x8 qa1 = *(const bf16x8*)(qk + qrow + h * 64 + 32 + g * 8);

        f32x4 acc[16];
#pragma unroll
        for (int tt = 0; tt < 16; ++tt) {
            const int key = key_base + tt * 16 + c;      // B-frag n = c
            const unsigned short* kp = qk + (size_t)(b * 1024 + key) * 2048
                                          + 1024 + h * 64 + g * 8;
            bf16x8 kb0 = *(const bf16x8*)(kp);
            bf16x8 kb1 = *(const bf16x8*)(kp + 32);
            f32x4 z = {0.f, 0.f, 0.f, 0.f};
            z = __builtin_amdgcn_mfma_f32_16x16x32_bf16(qa0, kb0, z, 0, 0, 0);
            z = __builtin_amdgcn_mfma_f32_16x16x32_bf16(qa1, kb1, z, 0, 0, 0);
            acc[tt] = z;
        }

        float rsum[4] = {0.f, 0.f, 0.f, 0.f};
#pragma unroll
        for (int tt = 0; tt < 16; ++tt) {
            const float kf = (float)(key_base + tt * 16 + c);
#pragma unroll
            for (int r = 0; r < 4; ++r) {
                const float qf = (float)(q0 + g * 4 + r);
                const float s = acc[tt][r] * 0.125f + td * fabsf(kf - qf);
                const float e = __expf(s);
                acc[tt][r] = e;
                rsum[r] += e;
            }
        }
#pragma unroll
        for (int r = 0; r < 4; ++r) {
            rsum[r] += __shfl_xor(rsum[r], 1, 64);
            rsum[r] += __shfl_xor(rsum[r], 2, 64);
            rsum[r] += __shfl_xor(rsum[r], 4, 64);
            rsum[r] += __shfl_xor(rsum[r], 8, 64);
        }
        if (c == 0) {
#pragma unroll
            for (int r = 0; r < 4; ++r) rs_s[w][g * 4 + r] = rsum[r];
        }
        __syncthreads();
        float invl[4];
#pragma unroll
        for (int r = 0; r < 4; ++r) {
            const int row = g * 4 + r;
            invl[r] = 1.0f / (rs_s[0][row] + rs_s[1][row] + rs_s[2][row] + rs_s[3][row]);
        }

#pragma unroll
        for (int tt = 0; tt < 16; ++tt) {
#pragma unroll
            for (int r = 0; r < 4; ++r) {
                const float wv = acc[tt][r] * invl[r];
                wsum[tt][r] += wv;
                P_s[g * 4 + r][key_base + tt * 16 + c] = f2bu(wv);
            }
        }
        __syncthreads();

        f32x4 accO = {0.f, 0.f, 0.f, 0.f};
        const unsigned short* vhp = vt + (size_t)((b * 16 + h) * 64 + w * 16 + c) * 1024;
#pragma unroll 8
        for (int ks = 0; ks < 32; ++ks) {
            bf16x8 pa = *(const bf16x8*)(&P_s[c][ks * 32 + g * 8]);
            bf16x8 vb = *(const bf16x8*)(vhp + ks * 32 + g * 8);
            accO = __builtin_amdgcn_mfma_f32_16x16x32_bf16(pa, vb, accO, 0, 0, 0);
        }
        unsigned short* op = attnb + (size_t)(b * 1024 + q0) * 1024 + h * 64 + w * 16 + c;
#pragma unroll
        for (int r = 0; r < 4; ++r)
            op[(size_t)(g * 4 + r) * 1024] = f2bu(accO[r]);
        __syncthreads();
    }

#pragma unroll
    for (int tt = 0; tt < 16; ++tt) {
#pragma unroll
        for (int r = 0; r < 4; ++r) {
            wout[(size_t)(b * 1024 + q0 + g * 4 + r) * 1024 + key_base + tt * 16 + c]
                = wsum[tt][r] * (1.0f / NHEAD);
        }
    }
}

// =====================================================================
// K3: outproj MFMA. y = attnb @ wob^T + bias + x   (bf16 in, fp32 out)
// =====================================================================
__global__ __launch_bounds__(256)
void outproj_mfma(const unsigned short* __restrict__ ab,   // [8192][1024]
                  const unsigned short* __restrict__ wob,  // [1024][1024]
                  const float* __restrict__ bias,
                  const float* __restrict__ X,
                  float* __restrict__ Y) {
    __shared__ unsigned short smem[8192];
    unsigned short* As = smem;
    unsigned short* Bs = smem + 4096;

    const int t = threadIdx.x;
    const int w = t >> 6, lane = t & 63;
    const int wm = w >> 1, wn = w & 1;
    const int g = lane >> 4, c = lane & 15;
    const int m0 = blockIdx.y * 128, n0 = blockIdx.x * 128;

    const int srow = t >> 2;
    const int scol = (t & 3) * 8;
    const unsigned short* ga = ab  + (size_t)(m0 + srow) * 1024 + scol;
    const unsigned short* gb = wob + (size_t)(n0 + srow) * 1024 + scol;

    f32x4 acc[4][4];
#pragma unroll
    for (int i = 0; i < 4; ++i)
#pragma unroll
        for (int j = 0; j < 4; ++j) acc[i][j] = (f32x4){0.f, 0.f, 0.f, 0.f};

    for (int k0 = 0; k0 < 1024; k0 += 32) {
        gl16(ga + k0,             As + t * 8);
        gl16(ga + 64 * 1024 + k0, As + 2048 + t * 8);
        gl16(gb + k0,             Bs + t * 8);
        gl16(gb + 64 * 1024 + k0, Bs + 2048 + t * 8);
        __syncthreads();
        bf16x8 af[4], bf[4];
#pragma unroll
        for (int i = 0; i < 4; ++i)
            af[i] = *(const bf16x8*)(As + (wm * 64 + i * 16 + c) * 32 + g * 8);
#pragma unroll
        for (int j = 0; j < 4; ++j)
            bf[j] = *(const bf16x8*)(Bs + (wn * 64 + j * 16 + c) * 32 + g * 8);
#pragma unroll
        for (int i = 0; i < 4; ++i)
#pragma unroll
            for (int j = 0; j < 4; ++j)
                acc[i][j] = __builtin_amdgcn_mfma_f32_16x16x32_bf16(af[i], bf[j], acc[i][j], 0, 0, 0);
        __syncthreads();
    }

    float bsv[4];
#pragma unroll
    for (int j = 0; j < 4; ++j) bsv[j] = bias[n0 + wn * 64 + j * 16 + c];

#pragma unroll
    for (int i = 0; i < 4; ++i) {
#pragma unroll
        for (int r = 0; r < 4; ++r) {
            const int m = m0 + wm * 64 + i * 16 + g * 4 + r;
#pragma unroll
            for (int j = 0; j < 4; ++j) {
                const int n = n0 + wn * 64 + j * 16 + c;
                Y[(size_t)m * 1024 + n] = acc[i][j][r] + bsv[j] + X[(size_t)m * 1024 + n];
            }
        }
    }
}

// =====================================================================
// K4: LayerNorm per row -> final out
// =====================================================================
__global__ __launch_bounds__(256)
void ln_kernel(const float* __restrict__ Y, const float* __restrict__ lnw,
               const float* __restrict__ lnb, float* __restrict__ out) {
    const int row = blockIdx.x, t = threadIdx.x;
    __shared__ float rs[256], rq[256];
    const float4 v = ((const float4*)(Y + (size_t)row * DMODEL))[t];
    rs[t] = v.x + v.y + v.z + v.w;
    rq[t] = v.x * v.x + v.y * v.y + v.z * v.z + v.w * v.w;
    __syncthreads();
    for (int off = 128; off > 0; off >>= 1) {
        if (t < off) { rs[t] += rs[t + off]; rq[t] += rq[t + off]; }
        __syncthreads();
    }
    const float mu   = rs[0] * (1.0f / DMODEL);
    const float var  = rq[0] * (1.0f / DMODEL) - mu * mu;
    const float rstd = rsqrtf(var + LN_EPS);
    const float4 w  = ((const float4*)lnw)[t];
    const float4 bb = ((const float4*)lnb)[t];
    float4 o;
    o.x = (v.x - mu) * rstd * w.x + bb.x;
    o.y = (v.y - mu) * rstd * w.y + bb.y;
    o.z = (v.z - mu) * rstd * w.z + bb.z;
    o.w = (v.w - mu) * rstd * w.w + bb.w;
    ((float4*)(out + (size_t)row * DMODEL))[t] = o;
}

// =====================================================================
extern "C" void kernel_launch(void* const* d_in, const int* in_sizes, int n_in,
                              void* d_out, int out_size, void* d_ws, size_t ws_size,
                              hipStream_t stream) {
    (void)in_sizes; (void)n_in; (void)out_size; (void)ws_size;
    const float* x    = (const float*)d_in[0];
    const float* td   = (const float*)d_in[1];
    const float* wqkv = (const float*)d_in[2];
    const float* bqkv = (const float*)d_in[3];
    const float* wo   = (const float*)d_in[4];
    const float* bo   = (const float*)d_in[5];
    const float* lnw  = (const float*)d_in[6];
    const float* lnb  = (const float*)d_in[7];

    float* out_ln = (float*)d_out;                         // final out [8192,1024]
    float* out_w  = (float*)d_out + (size_t)NROWS * SEQ;   // mean weights [8,1024,1024]

    // ws (peak 48 MiB, same as round 1's proven usage):
    //   qk bf16 [8192,2048] at 0 (32 MiB); vt bf16 [128*64,1024] at +32 MiB (16 MiB).
    //   y fp32 [8192,1024] reuses offset 0 after attn (qk dead).
    unsigned short* qk = (unsigned short*)d_ws;
    unsigned short* vt = qk + (size_t)NROWS * 2048;
    float*          y  = (float*)d_ws;

    // d_out used as scratch (stream-ordered, fully rewritten later):
    //   first half:  attnb bf16 (16.8 MB @0) + wob bf16 (2.1 MB @+16.8MB); LN overwrites.
    //   second half: xb bf16 (16.8 MB) + wqkvb bf16 (6.3 MB); wout overwrites after qkv.
    unsigned short* attnb = (unsigned short*)d_out;
    unsigned short* wob   = (unsigned short*)d_out + (size_t)NROWS * DMODEL;
    unsigned short* xb    = (unsigned short*)out_w;
    unsigned short* wqkvb = xb + (size_t)NROWS * DMODEL;

    cvt_bf16    <<<(NG_X + NG_WQ + NG_WO) / 256, 256, 0, stream>>>(x, wqkv, wo, xb, wqkvb, wob);
    qkv_mfma    <<<dim3(D3 / 128, NROWS / 128), 256, 0, stream>>>(xb, wqkvb, bqkv, qk, vt);
    attn_mfma   <<<dim3(SEQ / 16, BATCH),       256, 0, stream>>>(qk, vt, td, attnb, out_w);
    outproj_mfma<<<dim3(DMODEL / 128, NROWS / 128), 256, 0, stream>>>(attnb, wob, bo, x, y);
    ln_kernel   <<<NROWS,                       256, 0, stream>>>(y, lnw, lnb, out_ln);
}

// Round 4
// 505.886 us; speedup vs baseline: 8.9184x; 1.1303x over previous
//
#include <hip/hip_runtime.h>
#include <cstddef>

// Problem constants
#define BATCH   8
#define SEQ     1024
#define DMODEL  1024
#define NHEAD   16
#define HDIM    64
#define D3      3072
#define NROWS   (BATCH * SEQ)   // 8192
#define LN_EPS  1e-5f

typedef __attribute__((ext_vector_type(4))) float f32x4;
typedef __attribute__((ext_vector_type(8))) short bf16x8;

// ---------- bf16 helpers ----------
__device__ __forceinline__ float b2f(unsigned short u) {
    union { unsigned int i; float f; } v; v.i = ((unsigned int)u) << 16; return v.f;
}
__device__ __forceinline__ unsigned short f2bu(float f) {  // round-to-nearest-even
    union { float f; unsigned int i; } v; v.f = f;
    unsigned int r = v.i + 0x7fffu + ((v.i >> 16) & 1u);
    return (unsigned short)(r >> 16);
}
// async global->LDS, 16B per lane (wave-uniform base + lane*16)
__device__ __forceinline__ void gl16(const void* g, void* l) {
    __builtin_amdgcn_global_load_lds(
        (const __attribute__((address_space(1))) unsigned int*)g,
        (__attribute__((address_space(3))) unsigned int*)l, 16, 0, 0);
}

// =====================================================================
// K0: fp32 -> bf16 conversion of x, in_proj_w, out_proj_w
// =====================================================================
#define NG_X  1048576   // 8192*1024/8
#define NG_WQ 393216    // 3072*1024/8
#define NG_WO 131072    // 1024*1024/8
__global__ __launch_bounds__(256)
void cvt_bf16(const float* __restrict__ x, const float* __restrict__ wq,
              const float* __restrict__ wo,
              unsigned short* __restrict__ xb, unsigned short* __restrict__ wqb,
              unsigned short* __restrict__ wob) {
    const int gidx = blockIdx.x * 256 + threadIdx.x;
    const float* src; unsigned short* dst; size_t off;
    if (gidx < NG_X)              { src = x;  dst = xb;  off = (size_t)gidx * 8; }
    else if (gidx < NG_X + NG_WQ) { src = wq; dst = wqb; off = (size_t)(gidx - NG_X) * 8; }
    else                          { src = wo; dst = wob; off = (size_t)(gidx - NG_X - NG_WQ) * 8; }
    float4 v0 = *(const float4*)(src + off);
    float4 v1 = *(const float4*)(src + off + 4);
    uint4 pv;
    pv.x = f2bu(v0.x) | ((unsigned int)f2bu(v0.y) << 16);
    pv.y = f2bu(v0.z) | ((unsigned int)f2bu(v0.w) << 16);
    pv.z = f2bu(v1.x) | ((unsigned int)f2bu(v1.y) << 16);
    pv.w = f2bu(v1.z) | ((unsigned int)f2bu(v1.w) << 16);
    *(uint4*)(dst + off) = pv;
}

// =====================================================================
// K1: qkv MFMA GEMM. C[8192,3072] = xb @ wb^T + bias  (bf16 in, bf16 out)
// Q -> qh[(b*16+h)][tok][64], K -> kh[(b*16+h)][key][64]  (per-head slabs)
// V -> vt[(b*16+h)*64+d][key] transposed.
// 128x128 tile, BK=32, 4 waves (2x2), 16x16x32 MFMA, global_load_lds x16B.
// =====================================================================
__global__ __launch_bounds__(256)
void qkv_mfma(const unsigned short* __restrict__ xb,    // [8192][1024]
              const unsigned short* __restrict__ wb,    // [3072][1024]
              const float* __restrict__ bias,           // [3072]
              unsigned short* __restrict__ qh,          // [128][1024][64]
              unsigned short* __restrict__ kh,          // [128][1024][64]
              unsigned short* __restrict__ vt) {        // [128*64][1024]
    __shared__ unsigned short smem[8192];               // As 4096 | Bs 4096 (16 KB)
    unsigned short* As = smem;
    unsigned short* Bs = smem + 4096;

    const int t = threadIdx.x;
    const int w = t >> 6, lane = t & 63;
    const int wm = w >> 1, wn = w & 1;
    const int g = lane >> 4, c = lane & 15;
    const int m0 = blockIdx.y * 128, n0 = blockIdx.x * 128;

    const int srow = t >> 2;            // 0..63
    const int scol = (t & 3) * 8;       // 0,8,16,24
    const unsigned short* ga = xb + (size_t)(m0 + srow) * 1024 + scol;
    const unsigned short* gb = wb + (size_t)(n0 + srow) * 1024 + scol;

    f32x4 acc[4][4];
#pragma unroll
    for (int i = 0; i < 4; ++i)
#pragma unroll
        for (int j = 0; j < 4; ++j) acc[i][j] = (f32x4){0.f, 0.f, 0.f, 0.f};

    for (int k0 = 0; k0 < 1024; k0 += 32) {
        gl16(ga + k0,             As + t * 8);
        gl16(ga + 64 * 1024 + k0, As + 2048 + t * 8);
        gl16(gb + k0,             Bs + t * 8);
        gl16(gb + 64 * 1024 + k0, Bs + 2048 + t * 8);
        __syncthreads();                         // drains vmcnt -> tile visible
        bf16x8 af[4], bf[4];
#pragma unroll
        for (int i = 0; i < 4; ++i)
            af[i] = *(const bf16x8*)(As + (wm * 64 + i * 16 + c) * 32 + g * 8);
#pragma unroll
        for (int j = 0; j < 4; ++j)
            bf[j] = *(const bf16x8*)(Bs + (wn * 64 + j * 16 + c) * 32 + g * 8);
#pragma unroll
        for (int i = 0; i < 4; ++i)
#pragma unroll
            for (int j = 0; j < 4; ++j)
                acc[i][j] = __builtin_amdgcn_mfma_f32_16x16x32_bf16(af[i], bf[j], acc[i][j], 0, 0, 0);
        __syncthreads();                         // protect tile before next overwrite
    }

    float bsv[4];
#pragma unroll
    for (int j = 0; j < 4; ++j) bsv[j] = bias[n0 + wn * 64 + j * 16 + c];

    unsigned short* eslice = smem + w * 2048;    // 4 KB per-wave epilogue slice
    const int b_ = m0 >> 10;                     // batch (tile never straddles)

    if (n0 < 2048) {
        // ---- Q or K: per-head slab [128 slabs][1024 tok][64 d] ----
        const int ncl   = n0 + wn * 64;          // wave's 64-col slice = one head
        unsigned short* dst = (ncl < 1024)
            ? qh + ((size_t)(b_ * 16 + (ncl >> 6)) * 1024) * 64
            : kh + ((size_t)(b_ * 16 + ((ncl - 1024) >> 6)) * 1024) * 64;
#pragma unroll
        for (int half = 0; half < 2; ++half) {
#pragma unroll
            for (int ii = 0; ii < 2; ++ii) {
                const int i = half * 2 + ii;
#pragma unroll
                for (int j = 0; j < 4; ++j)
#pragma unroll
                    for (int r = 0; r < 4; ++r)
                        eslice[(ii * 16 + g * 4 + r) * 64 + j * 16 + c] = f2bu(acc[i][j][r] + bsv[j]);
            }
#pragma unroll
            for (int u = 0; u < 4; ++u) {
                const int mloc = u * 8 + (lane >> 3);       // 0..31
                const int ncol = (lane & 7) * 8;
                bf16x8 row = *(const bf16x8*)(eslice + mloc * 64 + ncol);
                const int tok = (m0 & 1023) + wm * 64 + half * 32 + mloc;
                *(bf16x8*)(dst + (size_t)tok * 64 + ncol) = row;
            }
        }
    } else {
        // ---- V: transposed into vt[(b*16+h)*64+d][key], XOR-swizzled LDS ----
        const int key0  = (m0 & 1023) + wm * 64;
        const int hbase = (n0 + wn * 64 - 2048) >> 6;
#pragma unroll
        for (int half = 0; half < 2; ++half) {
#pragma unroll
            for (int jj = 0; jj < 2; ++jj) {
                const int j = half * 2 + jj;
                const int nloc = jj * 16 + c;               // 0..31
#pragma unroll
                for (int i = 0; i < 4; ++i)
#pragma unroll
                    for (int r = 0; r < 4; ++r) {
                        const int mloc  = i * 16 + g * 4 + r;
                        const int mphys = mloc ^ ((nloc & 7) << 3);
                        eslice[nloc * 64 + mphys] = f2bu(acc[i][j][r] + bsv[j]);
                    }
            }
#pragma unroll
            for (int u = 0; u < 4; ++u) {
                const int nloc  = u * 8 + (lane >> 3);      // 0..31
                const int mb    = lane & 7;
                const int mphys = (mb ^ (nloc & 7)) * 8;
                bf16x8 row = *(const bf16x8*)(eslice + nloc * 64 + mphys);
                const int d = half * 32 + nloc;
                *(bf16x8*)(vt + ((size_t)((b_ * 16 + hbase) * 64 + d)) * 1024 + key0 + mb * 8) = row;
            }
        }
    }
}

// =====================================================================
// K2: MFMA attention. Block = (qtile of 16 rows, batch). 256 threads.
// Per-head slab layout: every frag load lands in a 2KB window (16 lines).
// Writes attn bf16 [8192,1024] and head-mean weights fp32 [8192,1024].
// =====================================================================
__global__ __launch_bounds__(256, 2)
void attn_mfma(const unsigned short* __restrict__ qh,   // [128][1024][64]
               const unsigned short* __restrict__ kh,   // [128][1024][64]
               const unsigned short* __restrict__ vt,   // [128][64][1024]
               const float* __restrict__ tdp,
               unsigned short* __restrict__ attnb,       // [8192][1024] bf16
               float* __restrict__ wout) {               // [8192][1024]
    const int qt = blockIdx.x;      // 0..63
    const int b  = blockIdx.y;      // 0..7
    const int t  = threadIdx.x;
    const int w  = t >> 6;          // wave 0..3
    const int lane = t & 63;
    const int g  = lane >> 4;       // quad group 0..3
    const int c  = lane & 15;

    const int q0 = qt * 16;
    const float td = -fabsf(tdp[0]);

    __shared__ unsigned short P_s[16][1032];   // e-values (unnormalized would also work)
    __shared__ float rs_s[4][16];              // per-wave row sums

    float wsum[16][4];                          // head-mean accumulator (C layout)
#pragma unroll
    for (int tt = 0; tt < 16; ++tt)
#pragma unroll
        for (int r = 0; r < 4; ++r) wsum[tt][r] = 0.f;

    const int key_base = w * 256;               // wave's key range in QK^T

    for (int h = 0; h < NHEAD; ++h) {
        const unsigned short* qslab = qh + (size_t)(b * 16 + h) * 1024 * 64;
        const unsigned short* kslab = kh + (size_t)(b * 16 + h) * 1024 * 64;

        // A-frags: Q rows within the head slab (2KB window per frag)
        bf16x8 qa0 = *(const bf16x8*)(qslab + (size_t)(q0 + c) * 64 + g * 8);
        bf16x8 qa1 = *(const bf16x8*)(qslab + (size_t)(q0 + c) * 64 + 32 + g * 8);

        f32x4 acc[16];
#pragma unroll
        for (int tt = 0; tt < 16; ++tt) {
            const int key = key_base + tt * 16 + c;      // B-frag n = c
            const unsigned short* kp = kslab + (size_t)key * 64 + g * 8;
            bf16x8 kb0 = *(const bf16x8*)(kp);
            bf16x8 kb1 = *(const bf16x8*)(kp + 32);
            f32x4 z = {0.f, 0.f, 0.f, 0.f};
            z = __builtin_amdgcn_mfma_f32_16x16x32_bf16(qa0, kb0, z, 0, 0, 0);
            z = __builtin_amdgcn_mfma_f32_16x16x32_bf16(qa1, kb1, z, 0, 0, 0);
            acc[tt] = z;
        }

        float rsum[4] = {0.f, 0.f, 0.f, 0.f};
#pragma unroll
        for (int tt = 0; tt < 16; ++tt) {
            const float kf = (float)(key_base + tt * 16 + c);
#pragma unroll
            for (int r = 0; r < 4; ++r) {
                const float qf = (float)(q0 + g * 4 + r);
                const float s = acc[tt][r] * 0.125f + td * fabsf(kf - qf);
                const float e = __expf(s);
                acc[tt][r] = e;
                rsum[r] += e;
            }
        }
#pragma unroll
        for (int r = 0; r < 4; ++r) {
            rsum[r] += __shfl_xor(rsum[r], 1, 64);
            rsum[r] += __shfl_xor(rsum[r], 2, 64);
            rsum[r] += __shfl_xor(rsum[r], 4, 64);
            rsum[r] += __shfl_xor(rsum[r], 8, 64);
        }
        if (c == 0) {
#pragma unroll
            for (int r = 0; r < 4; ++r) rs_s[w][g * 4 + r] = rsum[r];
        }
        __syncthreads();
        float invl[4];
#pragma unroll
        for (int r = 0; r < 4; ++r) {
            const int row = g * 4 + r;
            invl[r] = 1.0f / (rs_s[0][row] + rs_s[1][row] + rs_s[2][row] + rs_s[3][row]);
        }

#pragma unroll
        for (int tt = 0; tt < 16; ++tt) {
#pragma unroll
            for (int r = 0; r < 4; ++r) {
                const float wv = acc[tt][r] * invl[r];
                wsum[tt][r] += wv;
                P_s[g * 4 + r][key_base + tt * 16 + c] = f2bu(wv);
            }
        }
        __syncthreads();

        f32x4 accO = {0.f, 0.f, 0.f, 0.f};
        const unsigned short* vhp = vt + (size_t)((b * 16 + h) * 64 + w * 16 + c) * 1024;
#pragma unroll 8
        for (int ks = 0; ks < 32; ++ks) {
            bf16x8 pa = *(const bf16x8*)(&P_s[c][ks * 32 + g * 8]);
            bf16x8 vb = *(const bf16x8*)(vhp + ks * 32 + g * 8);
            accO = __builtin_amdgcn_mfma_f32_16x16x32_bf16(pa, vb, accO, 0, 0, 0);
        }
        unsigned short* op = attnb + (size_t)(b * 1024 + q0) * 1024 + h * 64 + w * 16 + c;
#pragma unroll
        for (int r = 0; r < 4; ++r)
            op[(size_t)(g * 4 + r) * 1024] = f2bu(accO[r]);
        __syncthreads();
    }

#pragma unroll
    for (int tt = 0; tt < 16; ++tt) {
#pragma unroll
        for (int r = 0; r < 4; ++r) {
            wout[(size_t)(b * 1024 + q0 + g * 4 + r) * 1024 + key_base + tt * 16 + c]
                = wsum[tt][r] * (1.0f / NHEAD);
        }
    }
}

// =====================================================================
// K3: outproj MFMA. y = attnb @ wob^T + bias + x   (bf16 in, fp32 out)
// =====================================================================
__global__ __launch_bounds__(256)
void outproj_mfma(const unsigned short* __restrict__ ab,   // [8192][1024]
                  const unsigned short* __restrict__ wob,  // [1024][1024]
                  const float* __restrict__ bias,
                  const float* __restrict__ X,
                  float* __restrict__ Y) {
    __shared__ unsigned short smem[8192];
    unsigned short* As = smem;
    unsigned short* Bs = smem + 4096;

    const int t = threadIdx.x;
    const int w = t >> 6, lane = t & 63;
    const int wm = w >> 1, wn = w & 1;
    const int g = lane >> 4, c = lane & 15;
    const int m0 = blockIdx.y * 128, n0 = blockIdx.x * 128;

    const int srow = t >> 2;
    const int scol = (t & 3) * 8;
    const unsigned short* ga = ab  + (size_t)(m0 + srow) * 1024 + scol;
    const unsigned short* gb = wob + (size_t)(n0 + srow) * 1024 + scol;

    f32x4 acc[4][4];
#pragma unroll
    for (int i = 0; i < 4; ++i)
#pragma unroll
        for (int j = 0; j < 4; ++j) acc[i][j] = (f32x4){0.f, 0.f, 0.f, 0.f};

    for (int k0 = 0; k0 < 1024; k0 += 32) {
        gl16(ga + k0,             As + t * 8);
        gl16(ga + 64 * 1024 + k0, As + 2048 + t * 8);
        gl16(gb + k0,             Bs + t * 8);
        gl16(gb + 64 * 1024 + k0, Bs + 2048 + t * 8);
        __syncthreads();
        bf16x8 af[4], bf[4];
#pragma unroll
        for (int i = 0; i < 4; ++i)
            af[i] = *(const bf16x8*)(As + (wm * 64 + i * 16 + c) * 32 + g * 8);
#pragma unroll
        for (int j = 0; j < 4; ++j)
            bf[j] = *(const bf16x8*)(Bs + (wn * 64 + j * 16 + c) * 32 + g * 8);
#pragma unroll
        for (int i = 0; i < 4; ++i)
#pragma unroll
            for (int j = 0; j < 4; ++j)
                acc[i][j] = __builtin_amdgcn_mfma_f32_16x16x32_bf16(af[i], bf[j], acc[i][j], 0, 0, 0);
        __syncthreads();
    }

    float bsv[4];
#pragma unroll
    for (int j = 0; j < 4; ++j) bsv[j] = bias[n0 + wn * 64 + j * 16 + c];

#pragma unroll
    for (int i = 0; i < 4; ++i) {
#pragma unroll
        for (int r = 0; r < 4; ++r) {
            const int m = m0 + wm * 64 + i * 16 + g * 4 + r;
#pragma unroll
            for (int j = 0; j < 4; ++j) {
                const int n = n0 + wn * 64 + j * 16 + c;
                Y[(size_t)m * 1024 + n] = acc[i][j][r] + bsv[j] + X[(size_t)m * 1024 + n];
            }
        }
    }
}

// =====================================================================
// K4: LayerNorm per row -> final out
// =====================================================================
__global__ __launch_bounds__(256)
void ln_kernel(const float* __restrict__ Y, const float* __restrict__ lnw,
               const float* __restrict__ lnb, float* __restrict__ out) {
    const int row = blockIdx.x, t = threadIdx.x;
    __shared__ float rs[256], rq[256];
    const float4 v = ((const float4*)(Y + (size_t)row * DMODEL))[t];
    rs[t] = v.x + v.y + v.z + v.w;
    rq[t] = v.x * v.x + v.y * v.y + v.z * v.z + v.w * v.w;
    __syncthreads();
    for (int off = 128; off > 0; off >>= 1) {
        if (t < off) { rs[t] += rs[t + off]; rq[t] += rq[t + off]; }
        __syncthreads();
    }
    const float mu   = rs[0] * (1.0f / DMODEL);
    const float var  = rq[0] * (1.0f / DMODEL) - mu * mu;
    const float rstd = rsqrtf(var + LN_EPS);
    const float4 w  = ((const float4*)lnw)[t];
    const float4 bb = ((const float4*)lnb)[t];
    float4 o;
    o.x = (v.x - mu) * rstd * w.x + bb.x;
    o.y = (v.y - mu) * rstd * w.y + bb.y;
    o.z = (v.z - mu) * rstd * w.z + bb.z;
    o.w = (v.w - mu) * rstd * w.w + bb.w;
    ((float4*)(out + (size_t)row * DMODEL))[t] = o;
}

// =====================================================================
extern "C" void kernel_launch(void* const* d_in, const int* in_sizes, int n_in,
                              void* d_out, int out_size, void* d_ws, size_t ws_size,
                              hipStream_t stream) {
    (void)in_sizes; (void)n_in; (void)out_size; (void)ws_size;
    const float* x    = (const float*)d_in[0];
    const float* td   = (const float*)d_in[1];
    const float* wqkv = (const float*)d_in[2];
    const float* bqkv = (const float*)d_in[3];
    const float* wo   = (const float*)d_in[4];
    const float* bo   = (const float*)d_in[5];
    const float* lnw  = (const float*)d_in[6];
    const float* lnb  = (const float*)d_in[7];

    float* out_ln = (float*)d_out;                         // final out [8192,1024]
    float* out_w  = (float*)d_out + (size_t)NROWS * SEQ;   // mean weights [8,1024,1024]

    // ws (peak 48 MiB):
    //   qh bf16 [128][1024][64] @0        (16 MiB)
    //   kh bf16 [128][1024][64] @+16 MiB  (16 MiB)
    //   vt bf16 [128*64][1024]  @+32 MiB  (16 MiB)
    //   y  fp32 [8192][1024] reuses offset 0 after attn (qh/kh dead).
    unsigned short* qh = (unsigned short*)d_ws;
    unsigned short* kh = qh + (size_t)128 * 1024 * 64;
    unsigned short* vt = kh + (size_t)128 * 1024 * 64;
    float*          y  = (float*)d_ws;

    // d_out used as scratch (stream-ordered, fully rewritten later):
    //   first half:  attnb bf16 (16.8 MB @0) + wob bf16 (2.1 MB @+16.8MB); LN overwrites.
    //   second half: xb bf16 (16.8 MB) + wqkvb bf16 (6.3 MB); wout overwrites after qkv.
    unsigned short* attnb = (unsigned short*)d_out;
    unsigned short* wob   = (unsigned short*)d_out + (size_t)NROWS * DMODEL;
    unsigned short* xb    = (unsigned short*)out_w;
    unsigned short* wqkvb = xb + (size_t)NROWS * DMODEL;

    cvt_bf16    <<<(NG_X + NG_WQ + NG_WO) / 256, 256, 0, stream>>>(x, wqkv, wo, xb, wqkvb, wob);
    qkv_mfma    <<<dim3(D3 / 128, NROWS / 128), 256, 0, stream>>>(xb, wqkvb, bqkv, qh, kh, vt);
    attn_mfma   <<<dim3(SEQ / 16, BATCH),       256, 0, stream>>>(qh, kh, vt, td, attnb, out_w);
    outproj_mfma<<<dim3(DMODEL / 128, NROWS / 128), 256, 0, stream>>>(attnb, wob, bo, x, y);
    ln_kernel   <<<NROWS,                       256, 0, stream>>>(y, lnw, lnb, out_ln);
}